// Round 6
// baseline (202.538 us; speedup 1.0000x reference)
//
#include <hip/hip_runtime.h>

#define INF_DELTA 1e10f
#define RM_EPS 1e-10f
#define LOG2E 1.4426950408889634f

typedef float floatx4 __attribute__((ext_vector_type(4)));

__device__ __forceinline__ int   f2i(float x){ union{float f;int i;}u; u.f=x; return u.i; }
__device__ __forceinline__ float i2f(int x)  { union{int i;float f;}u; u.i=x; return u.f; }

// DPP move within 16-lane rows. row_shr:N (0x110+N): lane i reads lane i-N.
// row_shl:N (0x100+N): lane i reads lane i+N. Invalid source lanes -> `old`.
template<int CTRL>
__device__ __forceinline__ float dpp_mov(float src, float old){
    return i2f(__builtin_amdgcn_update_dpp(f2i(old), f2i(src), CTRL, 0xF, 0xF, false));
}

__device__ __forceinline__ float softplus_log2(float x) {
    // log2(1+e^x) = relu(x)*log2e + log2(1 + exp2(-|x|*log2e))
    const float q  = __builtin_amdgcn_exp2f(-__builtin_fabsf(x) * LOG2E);
    const float l2 = __builtin_amdgcn_logf(1.0f + q);
    return __builtin_fmaf(__builtin_fmaxf(x, 0.0f), LOG2E, l2);
}

// 16 lanes per ray, 4 samples per lane; all cross-lane via DPP (no LDS).
__global__ __launch_bounds__(256) void raymarch_kernel(
    const float4* __restrict__ colors4,    // (n_rays, 48) as float4
    const float4* __restrict__ densities4, // (n_rays, 16)
    const float4* __restrict__ depths4,    // (n_rays, 16)
    float* __restrict__ rgb_out,           // (n_rays, 3)
    float* __restrict__ depth_out,         // (n_rays,)
    float4* __restrict__ weights4,         // (n_rays, 16)
    float* __restrict__ trans_out,         // (n_rays,)
    int n_rays)
{
    const int tid = threadIdx.x;
    const int sl  = tid & 15;                        // lane within 16-lane row
    const int ray = blockIdx.x * 16 + (tid >> 4);    // one ray per row
    if (ray >= n_rays) return;

    const long vbase = (long)ray * 16 + sl;

    // ---- single clustered load phase (all consumed before any cross-lane op) ----
    const float4 d4 = depths4[vbase];
    const float4 x4 = densities4[vbase];
    const float4* cp = colors4 + (long)ray * 48 + sl * 3;
    const float4 ca = cp[0], cb = cp[1], cc = cp[2];

    // deltas; last delta of the row needs next lane's first depth (DPP row_shl:1)
    const float dnext = dpp_mov<0x101>(d4.x, 0.0f);
    const float del0 = d4.y - d4.x;
    const float del1 = d4.z - d4.y;
    const float del2 = d4.w - d4.z;
    const float del3 = (sl == 15) ? INF_DELTA : (dnext - d4.w);

    // y_j = exp(-delta_j * softplus(x_j)); 4 independent chains
    const float y0 = __builtin_amdgcn_exp2f(-del0 * softplus_log2(x4.x));
    const float y1 = __builtin_amdgcn_exp2f(-del1 * softplus_log2(x4.y));
    const float y2 = __builtin_amdgcn_exp2f(-del2 * softplus_log2(x4.z));
    const float y3 = __builtin_amdgcn_exp2f(-del3 * softplus_log2(x4.w));

    const float t0 = y0 + RM_EPS, t1 = y1 + RM_EPS;
    const float t2 = y2 + RM_EPS, t3 = y3 + RM_EPS;

    // in-lane exclusive prefix products
    const float ex1 = t0, ex2 = t0 * t1, ex3 = ex2 * t2;
    const float ptot = ex3 * t3;

    // e_j = alpha_j * (in-lane exclusive prefix); w_j = e_j * Pexcl later
    const float e0 = (1.0f - y0);
    const float e1 = (1.0f - y1) * ex1;
    const float e2 = (1.0f - y2) * ex2;
    const float e3 = (1.0f - y3) * ex3;

    // per-lane partial sums — colors fully consumed BEFORE the scan
    float s0 = e0*ca.x + e1*ca.w + e2*cb.z + e3*cc.y;   // channel 0
    float s1 = e0*ca.y + e1*cb.x + e2*cb.w + e3*cc.z;   // channel 1
    float s2 = e0*ca.z + e1*cb.y + e2*cc.x + e3*cc.w;   // channel 2
    float s3 = e0*d4.x + e1*d4.y + e2*d4.z + e3*d4.w;   // depth

    // ---- cross-lane (all DPP, VALU pipe) ----
    // inclusive product scan of ptot over the 16-lane row
    float P = ptot;
    P *= dpp_mov<0x111>(P, 1.0f);   // row_shr:1
    P *= dpp_mov<0x112>(P, 1.0f);   // row_shr:2
    P *= dpp_mov<0x114>(P, 1.0f);   // row_shr:4
    P *= dpp_mov<0x118>(P, 1.0f);   // row_shr:8
    const float Pexcl = dpp_mov<0x111>(P, 1.0f);   // exclusive

    // weights (dense nontemporal float4 store via native vector type)
    floatx4 wv;
    wv.x = e0 * Pexcl; wv.y = e1 * Pexcl; wv.z = e2 * Pexcl; wv.w = e3 * Pexcl;
    __builtin_nontemporal_store(wv, (floatx4*)&weights4[vbase]);

    // row totals via DPP add-scans (lane 15 ends with the full sum)
    float v0 = Pexcl * s0, v1 = Pexcl * s1, v2 = Pexcl * s2, v3 = Pexcl * s3;
    v0 += dpp_mov<0x111>(v0, 0.0f); v0 += dpp_mov<0x112>(v0, 0.0f);
    v0 += dpp_mov<0x114>(v0, 0.0f); v0 += dpp_mov<0x118>(v0, 0.0f);
    v1 += dpp_mov<0x111>(v1, 0.0f); v1 += dpp_mov<0x112>(v1, 0.0f);
    v1 += dpp_mov<0x114>(v1, 0.0f); v1 += dpp_mov<0x118>(v1, 0.0f);
    v2 += dpp_mov<0x111>(v2, 0.0f); v2 += dpp_mov<0x112>(v2, 0.0f);
    v2 += dpp_mov<0x114>(v2, 0.0f); v2 += dpp_mov<0x118>(v2, 0.0f);
    v3 += dpp_mov<0x111>(v3, 0.0f); v3 += dpp_mov<0x112>(v3, 0.0f);
    v3 += dpp_mov<0x114>(v3, 0.0f); v3 += dpp_mov<0x118>(v3, 0.0f);

    if (sl == 15) {
        const long r3 = (long)ray * 3;
        rgb_out[r3 + 0] = v0;
        rgb_out[r3 + 1] = v1;
        rgb_out[r3 + 2] = v2;
        depth_out[ray]  = v3;
        trans_out[ray]  = P;      // lane 15's inclusive product = final transmittance
    }
}

extern "C" void kernel_launch(void* const* d_in, const int* in_sizes, int n_in,
                              void* d_out, int out_size, void* d_ws, size_t ws_size,
                              hipStream_t stream) {
    const float4* colors4    = (const float4*)d_in[0];
    const float4* densities4 = (const float4*)d_in[1];
    const float4* depths4    = (const float4*)d_in[2];

    const int n_rays = in_sizes[1] / 64;

    float* out      = (float*)d_out;
    float* rgb      = out;                              // n_rays*3
    float* depth_o  = rgb + (long)n_rays * 3;           // n_rays
    float4* weights = (float4*)(depth_o + n_rays);      // n_rays*16 float4
    float* trans    = (float*)(weights + (long)n_rays * 16);

    const int blocks = (n_rays + 15) / 16;   // 16 rays per 256-thread block
    raymarch_kernel<<<blocks, 256, 0, stream>>>(
        colors4, densities4, depths4, rgb, depth_o, weights, trans, n_rays);
}